// Round 20
// baseline (224.348 us; speedup 1.0000x reference)
//
#include <hip/hip_runtime.h>
#include <math.h>

#define BB 8
#define LL 4096
#define HH 512
#define NN 512
#define TT 192        // truncated FIR length
#define NS 96         // tap-pair steps (TT/2)
#define LT 16         // output rows per wave tile

typedef _Float16 half2_t __attribute__((ext_vector_type(2)));
typedef unsigned int u32;
typedef unsigned short u16;

// R8-measured best conv config: asm fdot2 ("v"-pinned).
#if defined(__AMDGCN__)
__device__ __forceinline__ float fdot2(half2_t a, half2_t b, float c) {
    asm("v_dot2_f32_f16 %0, %1, %2, %0" : "+v"(c) : "v"(a), "v"(b));
    return c;
}
#elif __has_builtin(__builtin_amdgcn_fdot2)
__device__ __forceinline__ float fdot2(half2_t a, half2_t b, float c) {
    return __builtin_amdgcn_fdot2(a, b, c, false);
}
#else
__device__ __forceinline__ float fdot2(half2_t a, half2_t b, float c) {
    return c + (float)a.x * (float)b.x + (float)a.y * (float)b.y;
}
#endif

// ---------------------------------------------------------------------------
// Kernel 1 (fused prep), 3 branches by blockIdx (unchanged).
#define LN_BLKS (BB * LL / 8)
__global__ __launch_bounds__(256) void prep_kernel(const float* __restrict__ x,
                                                   const float* __restrict__ w,
                                                   const float* __restrict__ bia,
                                                   const float* __restrict__ Cr,
                                                   const float* __restrict__ Ci,
                                                   const float* __restrict__ LR,
                                                   const float* __restrict__ LI,
                                                   u32* __restrict__ u2,
                                                   float2* __restrict__ Cpk,
                                                   float2* __restrict__ PQ) {
    __shared__ float tile[64][65];
    if (blockIdx.x >= LN_BLKS + 64) {
        int n = blockIdx.x - (LN_BLKS + 64);
        int t = threadIdx.x;
        if (t < TT) {
            float lr = -expf(LR[n]);
            float li = expf(LI[n]);
            float el = expf(lr);
            float sn, cs;
            sincosf(li, &sn, &cs);
            float nr = el * cs - 1.0f;
            float ni = el * sn;
            float inv = 1.0f / (lr * lr + li * li);
            float sr = (nr * lr + ni * li) * inv;   // s = (e^lam-1)/lam
            float si = (ni * lr - nr * li) * inv;
            float tf = (float)t;
            float e2 = expf(lr * tf);
            float s2, c2;
            sincosf(li * tf, &s2, &c2);
            float er = e2 * c2, ei = e2 * s2;       // w^t
            PQ[(size_t)n * TT + t] = make_float2(sr * er - si * ei, sr * ei + si * er);
        }
        return;
    }
    if (blockIdx.x >= LN_BLKS) {
        int tb = blockIdx.x - LN_BLKS;   // 0..63
        int h0 = (tb & 7) * 64;
        int n0 = (tb >> 3) * 64;
        int c = threadIdx.x & 63;
        int r0 = threadIdx.x >> 6;
        float vr[16], vi[16];
        #pragma unroll
        for (int i = 0; i < 16; ++i) {
            int r = r0 + i * 4;
            tile[r][c] = Cr[(size_t)(h0 + r) * NN + n0 + c];
        }
        __syncthreads();
        #pragma unroll
        for (int i = 0; i < 16; ++i) vr[i] = tile[c][r0 + i * 4];
        __syncthreads();
        #pragma unroll
        for (int i = 0; i < 16; ++i) {
            int r = r0 + i * 4;
            tile[r][c] = Ci[(size_t)(h0 + r) * NN + n0 + c];
        }
        __syncthreads();
        #pragma unroll
        for (int i = 0; i < 16; ++i) vi[i] = tile[c][r0 + i * 4];
        #pragma unroll
        for (int i = 0; i < 16; ++i) {
            int r = r0 + i * 4;
            Cpk[(size_t)(n0 + r) * HH + h0 + c] = make_float2(vr[i], vi[i]);
        }
        return;
    }
    int wave = threadIdx.x >> 6;
    int lane = threadIdx.x & 63;
    size_t pair = (size_t)blockIdx.x * 4 + wave;
    const float* xr0 = x + pair * 2 * HH;
    const float* xr1 = xr0 + HH;
    float4 a0 = *(const float4*)(xr0 + lane * 4);
    float4 a1 = *(const float4*)(xr0 + 256 + lane * 4);
    float4 b0 = *(const float4*)(xr1 + lane * 4);
    float4 b1 = *(const float4*)(xr1 + 256 + lane * 4);
    float sA  = a0.x + a0.y + a0.z + a0.w + a1.x + a1.y + a1.z + a1.w;
    float qA  = a0.x*a0.x + a0.y*a0.y + a0.z*a0.z + a0.w*a0.w
              + a1.x*a1.x + a1.y*a1.y + a1.z*a1.z + a1.w*a1.w;
    float sB  = b0.x + b0.y + b0.z + b0.w + b1.x + b1.y + b1.z + b1.w;
    float qB  = b0.x*b0.x + b0.y*b0.y + b0.z*b0.z + b0.w*b0.w
              + b1.x*b1.x + b1.y*b1.y + b1.z*b1.z + b1.w*b1.w;
    #pragma unroll
    for (int off = 1; off < 64; off <<= 1) {
        sA += __shfl_xor(sA, off, 64);
        qA += __shfl_xor(qA, off, 64);
        sB += __shfl_xor(sB, off, 64);
        qB += __shfl_xor(qB, off, 64);
    }
    float mA = sA * (1.0f / 512.0f);
    float rA = rsqrtf(qA * (1.0f / 512.0f) - mA * mA + 1e-5f);
    float mB = sB * (1.0f / 512.0f);
    float rB = rsqrtf(qB * (1.0f / 512.0f) - mB * mB + 1e-5f);
    float4 w0 = *(const float4*)(w + lane * 4);
    float4 w1 = *(const float4*)(w + 256 + lane * 4);
    float4 c0 = *(const float4*)(bia + lane * 4);
    float4 c1 = *(const float4*)(bia + 256 + lane * 4);
    uint4 o0, o1;
    {
        half2_t p;
        p.x = (_Float16)((a0.x - mA) * rA * w0.x + c0.x);
        p.y = (_Float16)((b0.x - mB) * rB * w0.x + c0.x);
        o0.x = __builtin_bit_cast(u32, p);
        p.x = (_Float16)((a0.y - mA) * rA * w0.y + c0.y);
        p.y = (_Float16)((b0.y - mB) * rB * w0.y + c0.y);
        o0.y = __builtin_bit_cast(u32, p);
        p.x = (_Float16)((a0.z - mA) * rA * w0.z + c0.z);
        p.y = (_Float16)((b0.z - mB) * rB * w0.z + c0.z);
        o0.z = __builtin_bit_cast(u32, p);
        p.x = (_Float16)((a0.w - mA) * rA * w0.w + c0.w);
        p.y = (_Float16)((b0.w - mB) * rB * w0.w + c0.w);
        o0.w = __builtin_bit_cast(u32, p);
        p.x = (_Float16)((a1.x - mA) * rA * w1.x + c1.x);
        p.y = (_Float16)((b1.x - mB) * rB * w1.x + c1.x);
        o1.x = __builtin_bit_cast(u32, p);
        p.x = (_Float16)((a1.y - mA) * rA * w1.y + c1.y);
        p.y = (_Float16)((b1.y - mB) * rB * w1.y + c1.y);
        o1.y = __builtin_bit_cast(u32, p);
        p.x = (_Float16)((a1.z - mA) * rA * w1.z + c1.z);
        p.y = (_Float16)((b1.z - mB) * rB * w1.z + c1.z);
        o1.z = __builtin_bit_cast(u32, p);
        p.x = (_Float16)((a1.w - mA) * rA * w1.w + c1.w);
        p.y = (_Float16)((b1.w - mB) * rB * w1.w + c1.w);
        o1.w = __builtin_bit_cast(u32, p);
    }
    *(uint4*)(u2 + pair * HH + lane * 4) = o0;
    *(uint4*)(u2 + pair * HH + 256 + lane * 4) = o1;
}

// ---------------------------------------------------------------------------
// Kernel 2 (R10, kept): 384 blocks x 512 thr, 4-way n-split + LDS reduce.
__global__ __launch_bounds__(512) void build_kt(const float2* __restrict__ Cpk,
                                                const float2* __restrict__ PQ,
                                                float* __restrict__ KT) {
    __shared__ float red[3][128][2];
    int blk = blockIdx.x;               // 96 t-pairs * 4 h-quarters
    int t0 = (blk >> 2) * 2;
    int hq = blk & 3;
    int hh = threadIdx.x & 127;
    int nq = threadIdx.x >> 7;          // 0..3: n-quarter (wave-uniform)
    int h = hq * 128 + hh;
    float k0 = 0.0f, k1 = 0.0f;
    const float4* pq4 = (const float4*)PQ;
    int pqoff = t0 >> 1;
    int n0 = nq * 128;
    #pragma unroll 8
    for (int n = n0; n < n0 + 128; ++n) {
        float2 c = Cpk[(size_t)n * HH + h];
        float4 f = pq4[(size_t)n * (TT / 2) + pqoff];   // (P[t0],Q[t0],P[t0+1],Q[t0+1])
        k0 = fmaf(c.x, f.x, k0);
        k0 = fmaf(-c.y, f.y, k0);
        k1 = fmaf(c.x, f.z, k1);
        k1 = fmaf(-c.y, f.w, k1);
    }
    if (nq) { red[nq - 1][hh][0] = k0; red[nq - 1][hh][1] = k1; }
    __syncthreads();
    if (nq == 0) {
        #pragma unroll
        for (int i = 0; i < 3; ++i) { k0 += red[i][hh][0]; k1 += red[i][hh][1]; }
        KT[(size_t)t0 * HH + h] = k0;
        KT[(size_t)(t0 + 1) * HH + h] = k1;
    }
}

// ---------------------------------------------------------------------------
// Kernel 3 (R19): WITHIN-RUN A/B on the tap-read stall theory.
//   A (V=0, batches 0-3): R15-exact per-step uint2 tap read (proven base).
//   B (V=1, batches 4-7): PAIRED-TAP b128 layout - taps for steps (2j,2j+1)
//     in one uint4 -> 1 ds_read_b128 per 2 steps, distance-1 prefetch.
//     2 steps = 32 dot2 = 128cyc >= 120cyc LDS latency (R16's 64cyc never
//     covered it); tap-read count halved.
// Read: B/A dispatch ratio, contention-controlled (R14 method).
// pack_k remains fused in the stage of both variants.

template <bool PRED>
__device__ __forceinline__ u32 load_v(const u32* __restrict__ ub2, int vi) {
    int c = vi;
    if (PRED && c < 0) c = 0;
    u32 val = ub2[(size_t)c * HH];
    if (PRED && vi < 0) val = 0u;
    return val;
}

#define SLOT(p) ((p) < 16 ? W[(p)] : X[(p) - 16])

// --- Variant 0 block: per-step uint2 read (R15 exact) ---
template <bool PRED, bool LOADU>
__device__ __forceinline__ void conv_block0(const u32* __restrict__ ub2,
                                            const uint2* klds,
                                            float (&acc)[LT], u32 (&W)[16], u32 (&X)[16],
                                            int ubase, int soff) {
    #pragma unroll
    for (int k = 0; k < 16; ++k) {
        u32 nv = 0u;
        if (LOADU) nv = load_v<PRED>(ub2, ubase + k);
        uint2 kq = klds[(soff + k) * 64];
        half2_t kx = __builtin_bit_cast(half2_t, kq.x);
        half2_t ky = __builtin_bit_cast(half2_t, kq.y);
        #pragma unroll
        for (int m = 0; m < 8; ++m) {
            half2_t ve = __builtin_bit_cast(half2_t, SLOT(k + m));
            half2_t vo = __builtin_bit_cast(half2_t, SLOT(k + m + 1));
            acc[2 * m]     = fdot2(ve, ky, acc[2 * m]);
            acc[2 * m + 1] = fdot2(vo, kx, acc[2 * m + 1]);
        }
        if (LOADU) W[k] = nv;
    }
}

// --- Variant 1 block: paired-tap uint4 read, distance-1 prefetch ---
template <bool PRED, bool LOADU>
__device__ __forceinline__ void conv_block1(const u32* __restrict__ ub2,
                                            const uint4* klds4,
                                            float (&acc)[LT], u32 (&W)[16], u32 (&X)[16],
                                            int ubase, int soff) {
    int j0 = soff >> 1;                  // 8 step-pairs per block
    uint4 T = klds4[j0 * 64];
    #pragma unroll
    for (int jj = 0; jj < 8; ++jj) {
        uint4 Tn = T;
        if (jj < 7) Tn = klds4[(j0 + jj + 1) * 64];
        int k0i = 2 * jj;
        u32 nv0 = 0u, nv1 = 0u;
        if (LOADU) {
            nv0 = load_v<PRED>(ub2, ubase + k0i);
            nv1 = load_v<PRED>(ub2, ubase + k0i + 1);
        }
        // even step k = 2jj: kx = T.x, ky = T.y
        {
            half2_t kx = __builtin_bit_cast(half2_t, T.x);
            half2_t ky = __builtin_bit_cast(half2_t, T.y);
            #pragma unroll
            for (int m = 0; m < 8; ++m) {
                half2_t ve = __builtin_bit_cast(half2_t, SLOT(k0i + m));
                half2_t vo = __builtin_bit_cast(half2_t, SLOT(k0i + m + 1));
                acc[2 * m]     = fdot2(ve, ky, acc[2 * m]);
                acc[2 * m + 1] = fdot2(vo, kx, acc[2 * m + 1]);
            }
            if (LOADU) W[k0i] = nv0;
        }
        // odd step k = 2jj+1: kx = T.z, ky = T.w
        {
            int k = k0i + 1;
            half2_t kx = __builtin_bit_cast(half2_t, T.z);
            half2_t ky = __builtin_bit_cast(half2_t, T.w);
            #pragma unroll
            for (int m = 0; m < 8; ++m) {
                half2_t ve = __builtin_bit_cast(half2_t, SLOT(k + m));
                half2_t vo = __builtin_bit_cast(half2_t, SLOT(k + m + 1));
                acc[2 * m]     = fdot2(ve, ky, acc[2 * m]);
                acc[2 * m + 1] = fdot2(vo, kx, acc[2 * m + 1]);
            }
            if (LOADU) W[k] = nv1;
        }
        T = Tn;
    }
}

template <bool PRED, int V>
__device__ __forceinline__ void conv_all(const u32* __restrict__ ub2,
                                         const void* klds_v,
                                         float (&acc)[LT], u32 (&A)[16], u32 (&B)[16],
                                         int Vm1) {
    #pragma unroll
    for (int j = 0; j < 16; ++j) A[j] = load_v<PRED>(ub2, Vm1 + j);
    #pragma unroll
    for (int j = 0; j < 16; ++j) B[j] = load_v<PRED>(ub2, Vm1 + 16 + j);
    if constexpr (V == 0) {
        const uint2* klds = (const uint2*)klds_v;
        conv_block0<PRED, true >(ub2, klds, acc, A, B, Vm1 + 32, 0);
        conv_block0<PRED, true >(ub2, klds, acc, B, A, Vm1 + 48, 16);
        conv_block0<PRED, true >(ub2, klds, acc, A, B, Vm1 + 64, 32);
        conv_block0<PRED, true >(ub2, klds, acc, B, A, Vm1 + 80, 48);
        conv_block0<PRED, true >(ub2, klds, acc, A, B, Vm1 + 96, 64);
        conv_block0<PRED, false>(ub2, klds, acc, B, A, 0, 80);
    } else {
        const uint4* klds4 = (const uint4*)klds_v;
        conv_block1<PRED, true >(ub2, klds4, acc, A, B, Vm1 + 32, 0);
        conv_block1<PRED, true >(ub2, klds4, acc, B, A, Vm1 + 48, 16);
        conv_block1<PRED, true >(ub2, klds4, acc, A, B, Vm1 + 64, 32);
        conv_block1<PRED, true >(ub2, klds4, acc, B, A, Vm1 + 80, 48);
        conv_block1<PRED, true >(ub2, klds4, acc, A, B, Vm1 + 96, 64);
        conv_block1<PRED, false>(ub2, klds4, acc, B, A, 0, 80);
    }
}

template <int V>
__global__ __launch_bounds__(512, 2) void conv_kernel(const u32* __restrict__ u2,
                                                      const float* __restrict__ KT,
                                                      const float* __restrict__ Dp,
                                                      float* __restrict__ y,
                                                      int bbase) {
    __shared__ uint4 KLS[48 * 64];       // 48 KB (V0: uint2[96*64] view)
    int tid = threadIdx.x;
    int lane = tid & 63;
    int g = tid >> 6;                    // wave = l-subtile (0..7)
    int blk = blockIdx.x;                // 1024 blocks: 8 hg x 32 tg x 4 b
    int hg = blk & 7;
    int tg = (blk >> 3) & 31;
    int b = bbase + (blk >> 8);
    int h = hg * 64 + lane;
    int l0 = (tg * 8 + g) * LT;
    const float* ktg = KT + hg * 64;
    if constexpr (V == 0) {
        // stage as uint2 KL[s*64+hh], inline pack (R15 exact)
        uint2* KL = (uint2*)KLS;
        #pragma unroll
        for (int it = 0; it < 6; ++it) {
            int i = it * 512 + tid;      // uint4 index, 3072 total
            int s = i >> 5;
            int q = i & 31;
            int hh2 = q * 2;
            float2 k1 = *(const float2*)(ktg + (size_t)(191 - 2 * s) * HH + hh2);
            float2 k0 = *(const float2*)(ktg + (size_t)(190 - 2 * s) * HH + hh2);
            float2 k2 = make_float2(0.0f, 0.0f);
            if (s > 0) k2 = *(const float2*)(ktg + (size_t)(192 - 2 * s) * HH + hh2);
            half2_t ax, ay, bx, by;
            ax.x = (_Float16)k1.x; ax.y = (_Float16)k0.x;
            ay.x = (_Float16)k2.x; ay.y = (_Float16)k1.x;
            bx.x = (_Float16)k1.y; bx.y = (_Float16)k0.y;
            by.x = (_Float16)k2.y; by.y = (_Float16)k1.y;
            uint4 v = make_uint4(__builtin_bit_cast(u32, ax), __builtin_bit_cast(u32, ay),
                                 __builtin_bit_cast(u32, bx), __builtin_bit_cast(u32, by));
            *(uint4*)(&KL[s * 64 + q * 2]) = v;
        }
    } else {
        // stage as uint4 KL4[j*64+hh] = (kx(2j),ky(2j),kx(2j+1),ky(2j+1))
        #pragma unroll
        for (int it = 0; it < 6; ++it) {
            int i = it * 512 + tid;      // entry index, 3072 total
            int j = i >> 6;
            int hh = i & 63;
            int tb = 188 - 4 * j;        // K indices tb..tb+4 used
            float k188 = ktg[(size_t)(tb + 0) * HH + hh];
            float k189 = ktg[(size_t)(tb + 1) * HH + hh];
            float k190 = ktg[(size_t)(tb + 2) * HH + hh];
            float k191 = ktg[(size_t)(tb + 3) * HH + hh];
            float k192 = (j > 0) ? ktg[(size_t)(tb + 4) * HH + hh] : 0.0f;
            half2_t x0, y0, x1, y1;
            x0.x = (_Float16)k191; x0.y = (_Float16)k190;   // kx(2j)
            y0.x = (_Float16)k192; y0.y = (_Float16)k191;   // ky(2j)
            x1.x = (_Float16)k189; x1.y = (_Float16)k188;   // kx(2j+1)
            y1.x = (_Float16)k190; y1.y = (_Float16)k189;   // ky(2j+1)
            KLS[j * 64 + hh] = make_uint4(__builtin_bit_cast(u32, x0), __builtin_bit_cast(u32, y0),
                                          __builtin_bit_cast(u32, x1), __builtin_bit_cast(u32, y1));
        }
    }
    __syncthreads();
    const u32* ub2 = u2 + (size_t)b * (LL / 2) * HH + h;
    const void* klds_v = (V == 0) ? (const void*)&((const uint2*)KLS)[lane]
                                  : (const void*)&KLS[lane];
    int Vm1 = l0 / 2 - NS;
    float acc[LT];
    u32 A[16], B[16];
    #pragma unroll
    for (int j = 0; j < LT; ++j) acc[j] = 0.0f;
    if (l0 >= TT) {
        conv_all<false, V>(ub2, klds_v, acc, A, B, Vm1);
    } else {
        conv_all<true, V>(ub2, klds_v, acc, A, B, Vm1);
    }
    float dv = Dp[h];
    float k0f = KT[h];          // K[0]
    float ce = k0f + dv;
    float* yb = y + ((size_t)b * LL + l0) * HH + h;
    // A[m] = v[l0/2+m] = (u[l0+2m], u[l0+2m+1])
    #pragma unroll
    for (int m = 0; m < 8; ++m) {
        half2_t av = __builtin_bit_cast(half2_t, A[m]);
        float ue = (float)av.x;
        float uo = (float)av.y;
        yb[(size_t)(2 * m) * HH]     = acc[2 * m] + ce * ue;
        yb[(size_t)(2 * m + 1) * HH] = acc[2 * m + 1] + dv * uo;
    }
}

// ---------------------------------------------------------------------------
extern "C" void kernel_launch(void* const* d_in, const int* in_sizes, int n_in,
                              void* d_out, int out_size, void* d_ws, size_t ws_size,
                              hipStream_t stream) {
    const float* x   = (const float*)d_in[0];
    const float* lnw = (const float*)d_in[1];
    const float* lnb = (const float*)d_in[2];
    const float* LR  = (const float*)d_in[3];
    const float* LI  = (const float*)d_in[4];
    const float* Cr  = (const float*)d_in[5];
    const float* Ci  = (const float*)d_in[6];
    const float* Dp  = (const float*)d_in[7];
    float* y  = (float*)d_out;

    float2* Cpk = (float2*)d_ws;                      // NN*HH float2   (2 MB)
    float2* PQ  = Cpk + (size_t)NN * HH;              // NN*TT float2   (0.75 MB)
    float*  KT  = (float*)(PQ + (size_t)NN * TT);     // TT*HH          (384 KB)
    uint2*  KQ  = (uint2*)(KT + (size_t)TT * HH);     // (unused; layout keep)
    u32*    u2  = (u32*)(KQ + (size_t)NS * HH);       // BB*(LL/2)*HH + 16-row pad

    prep_kernel<<<LN_BLKS + 64 + NN, 256, 0, stream>>>(x, lnw, lnb, Cr, Ci,
                                                       LR, LI, u2, Cpk, PQ);
    build_kt<<<(TT / 2) * 4, 512, 0, stream>>>(Cpk, PQ, KT);
    // A/B: batches 0-3 = per-step taps (R15), 4-7 = paired b128 taps
    conv_kernel<0><<<(BB / 2) * (LL / (8 * LT)) * 8, 512, 0, stream>>>(u2, KT, Dp, y, 0);
    conv_kernel<1><<<(BB / 2) * (LL / (8 * LT)) * 8, 512, 0, stream>>>(u2, KT, Dp, y, 4);
}

// Round 21
// 218.482 us; speedup vs baseline: 1.0269x; 1.0269x over previous
//
#include <hip/hip_runtime.h>
#include <math.h>

#define BB 8
#define LL 4096
#define HH 512
#define NN 512
#define TT 192        // truncated FIR length
#define NS 96         // tap-pair steps (TT/2)
#define LT 16         // output rows per wave tile

typedef _Float16 half2_t __attribute__((ext_vector_type(2)));
typedef unsigned int u32;
typedef unsigned short u16;

// R8-measured best conv config: asm fdot2 ("v"-pinned).
#if defined(__AMDGCN__)
__device__ __forceinline__ float fdot2(half2_t a, half2_t b, float c) {
    asm("v_dot2_f32_f16 %0, %1, %2, %0" : "+v"(c) : "v"(a), "v"(b));
    return c;
}
#elif __has_builtin(__builtin_amdgcn_fdot2)
__device__ __forceinline__ float fdot2(half2_t a, half2_t b, float c) {
    return __builtin_amdgcn_fdot2(a, b, c, false);
}
#else
__device__ __forceinline__ float fdot2(half2_t a, half2_t b, float c) {
    return c + (float)a.x * (float)b.x + (float)a.y * (float)b.y;
}
#endif

// ---------------------------------------------------------------------------
// Kernel 1 (fused prep), 3 branches by blockIdx (unchanged).
#define LN_BLKS (BB * LL / 8)
__global__ __launch_bounds__(256) void prep_kernel(const float* __restrict__ x,
                                                   const float* __restrict__ w,
                                                   const float* __restrict__ bia,
                                                   const float* __restrict__ Cr,
                                                   const float* __restrict__ Ci,
                                                   const float* __restrict__ LR,
                                                   const float* __restrict__ LI,
                                                   u32* __restrict__ u2,
                                                   float2* __restrict__ Cpk,
                                                   float2* __restrict__ PQ) {
    __shared__ float tile[64][65];
    if (blockIdx.x >= LN_BLKS + 64) {
        int n = blockIdx.x - (LN_BLKS + 64);
        int t = threadIdx.x;
        if (t < TT) {
            float lr = -expf(LR[n]);
            float li = expf(LI[n]);
            float el = expf(lr);
            float sn, cs;
            sincosf(li, &sn, &cs);
            float nr = el * cs - 1.0f;
            float ni = el * sn;
            float inv = 1.0f / (lr * lr + li * li);
            float sr = (nr * lr + ni * li) * inv;   // s = (e^lam-1)/lam
            float si = (ni * lr - nr * li) * inv;
            float tf = (float)t;
            float e2 = expf(lr * tf);
            float s2, c2;
            sincosf(li * tf, &s2, &c2);
            float er = e2 * c2, ei = e2 * s2;       // w^t
            PQ[(size_t)n * TT + t] = make_float2(sr * er - si * ei, sr * ei + si * er);
        }
        return;
    }
    if (blockIdx.x >= LN_BLKS) {
        int tb = blockIdx.x - LN_BLKS;   // 0..63
        int h0 = (tb & 7) * 64;
        int n0 = (tb >> 3) * 64;
        int c = threadIdx.x & 63;
        int r0 = threadIdx.x >> 6;
        float vr[16], vi[16];
        #pragma unroll
        for (int i = 0; i < 16; ++i) {
            int r = r0 + i * 4;
            tile[r][c] = Cr[(size_t)(h0 + r) * NN + n0 + c];
        }
        __syncthreads();
        #pragma unroll
        for (int i = 0; i < 16; ++i) vr[i] = tile[c][r0 + i * 4];
        __syncthreads();
        #pragma unroll
        for (int i = 0; i < 16; ++i) {
            int r = r0 + i * 4;
            tile[r][c] = Ci[(size_t)(h0 + r) * NN + n0 + c];
        }
        __syncthreads();
        #pragma unroll
        for (int i = 0; i < 16; ++i) vi[i] = tile[c][r0 + i * 4];
        #pragma unroll
        for (int i = 0; i < 16; ++i) {
            int r = r0 + i * 4;
            Cpk[(size_t)(n0 + r) * HH + h0 + c] = make_float2(vr[i], vi[i]);
        }
        return;
    }
    int wave = threadIdx.x >> 6;
    int lane = threadIdx.x & 63;
    size_t pair = (size_t)blockIdx.x * 4 + wave;
    const float* xr0 = x + pair * 2 * HH;
    const float* xr1 = xr0 + HH;
    float4 a0 = *(const float4*)(xr0 + lane * 4);
    float4 a1 = *(const float4*)(xr0 + 256 + lane * 4);
    float4 b0 = *(const float4*)(xr1 + lane * 4);
    float4 b1 = *(const float4*)(xr1 + 256 + lane * 4);
    float sA  = a0.x + a0.y + a0.z + a0.w + a1.x + a1.y + a1.z + a1.w;
    float qA  = a0.x*a0.x + a0.y*a0.y + a0.z*a0.z + a0.w*a0.w
              + a1.x*a1.x + a1.y*a1.y + a1.z*a1.z + a1.w*a1.w;
    float sB  = b0.x + b0.y + b0.z + b0.w + b1.x + b1.y + b1.z + b1.w;
    float qB  = b0.x*b0.x + b0.y*b0.y + b0.z*b0.z + b0.w*b0.w
              + b1.x*b1.x + b1.y*b1.y + b1.z*b1.z + b1.w*b1.w;
    #pragma unroll
    for (int off = 1; off < 64; off <<= 1) {
        sA += __shfl_xor(sA, off, 64);
        qA += __shfl_xor(qA, off, 64);
        sB += __shfl_xor(sB, off, 64);
        qB += __shfl_xor(qB, off, 64);
    }
    float mA = sA * (1.0f / 512.0f);
    float rA = rsqrtf(qA * (1.0f / 512.0f) - mA * mA + 1e-5f);
    float mB = sB * (1.0f / 512.0f);
    float rB = rsqrtf(qB * (1.0f / 512.0f) - mB * mB + 1e-5f);
    float4 w0 = *(const float4*)(w + lane * 4);
    float4 w1 = *(const float4*)(w + 256 + lane * 4);
    float4 c0 = *(const float4*)(bia + lane * 4);
    float4 c1 = *(const float4*)(bia + 256 + lane * 4);
    uint4 o0, o1;
    {
        half2_t p;
        p.x = (_Float16)((a0.x - mA) * rA * w0.x + c0.x);
        p.y = (_Float16)((b0.x - mB) * rB * w0.x + c0.x);
        o0.x = __builtin_bit_cast(u32, p);
        p.x = (_Float16)((a0.y - mA) * rA * w0.y + c0.y);
        p.y = (_Float16)((b0.y - mB) * rB * w0.y + c0.y);
        o0.y = __builtin_bit_cast(u32, p);
        p.x = (_Float16)((a0.z - mA) * rA * w0.z + c0.z);
        p.y = (_Float16)((b0.z - mB) * rB * w0.z + c0.z);
        o0.z = __builtin_bit_cast(u32, p);
        p.x = (_Float16)((a0.w - mA) * rA * w0.w + c0.w);
        p.y = (_Float16)((b0.w - mB) * rB * w0.w + c0.w);
        o0.w = __builtin_bit_cast(u32, p);
        p.x = (_Float16)((a1.x - mA) * rA * w1.x + c1.x);
        p.y = (_Float16)((b1.x - mB) * rB * w1.x + c1.x);
        o1.x = __builtin_bit_cast(u32, p);
        p.x = (_Float16)((a1.y - mA) * rA * w1.y + c1.y);
        p.y = (_Float16)((b1.y - mB) * rB * w1.y + c1.y);
        o1.y = __builtin_bit_cast(u32, p);
        p.x = (_Float16)((a1.z - mA) * rA * w1.z + c1.z);
        p.y = (_Float16)((b1.z - mB) * rB * w1.z + c1.z);
        o1.z = __builtin_bit_cast(u32, p);
        p.x = (_Float16)((a1.w - mA) * rA * w1.w + c1.w);
        p.y = (_Float16)((b1.w - mB) * rB * w1.w + c1.w);
        o1.w = __builtin_bit_cast(u32, p);
    }
    *(uint4*)(u2 + pair * HH + lane * 4) = o0;
    *(uint4*)(u2 + pair * HH + 256 + lane * 4) = o1;
}

// ---------------------------------------------------------------------------
// Kernel 2 (R10, kept): 384 blocks x 512 thr, 4-way n-split + LDS reduce.
__global__ __launch_bounds__(512) void build_kt(const float2* __restrict__ Cpk,
                                                const float2* __restrict__ PQ,
                                                float* __restrict__ KT) {
    __shared__ float red[3][128][2];
    int blk = blockIdx.x;               // 96 t-pairs * 4 h-quarters
    int t0 = (blk >> 2) * 2;
    int hq = blk & 3;
    int hh = threadIdx.x & 127;
    int nq = threadIdx.x >> 7;          // 0..3: n-quarter (wave-uniform)
    int h = hq * 128 + hh;
    float k0 = 0.0f, k1 = 0.0f;
    const float4* pq4 = (const float4*)PQ;
    int pqoff = t0 >> 1;
    int n0 = nq * 128;
    #pragma unroll 8
    for (int n = n0; n < n0 + 128; ++n) {
        float2 c = Cpk[(size_t)n * HH + h];
        float4 f = pq4[(size_t)n * (TT / 2) + pqoff];   // (P[t0],Q[t0],P[t0+1],Q[t0+1])
        k0 = fmaf(c.x, f.x, k0);
        k0 = fmaf(-c.y, f.y, k0);
        k1 = fmaf(c.x, f.z, k1);
        k1 = fmaf(-c.y, f.w, k1);
    }
    if (nq) { red[nq - 1][hh][0] = k0; red[nq - 1][hh][1] = k1; }
    __syncthreads();
    if (nq == 0) {
        #pragma unroll
        for (int i = 0; i < 3; ++i) { k0 += red[i][hh][0]; k1 += red[i][hh][1]; }
        KT[(size_t)t0 * HH + h] = k0;
        KT[(size_t)(t0 + 1) * HH + h] = k1;
    }
}

// ---------------------------------------------------------------------------
// Kernel 3 (R21): PAIRED-TAP conv promoted to full grid.
// R20 A/B verdict: slowest-5 dispatches all variant A (per-step uint2 taps,
// VGPR=40) at 43.1-44.4us; paired-b128 variant B entirely below the cutoff
// (P~3% if A==B) -> B faster.  Mechanism: taps for steps (2j,2j+1) in one
// uint4 -> 1 ds_read_b128 per 2 steps with distance-1 prefetch; 2 steps =
// 32 dot2 = 128cyc >= 120cyc LDS latency (per-step 64cyc never covered it),
// and tap-read count halved.  Single dispatch, 2048 blocks, 8 batches.
// pack_k stays fused into the stage (uint4 tap layout built from KT inline).

template <bool PRED>
__device__ __forceinline__ u32 load_v(const u32* __restrict__ ub2, int vi) {
    int c = vi;
    if (PRED && c < 0) c = 0;
    u32 val = ub2[(size_t)c * HH];
    if (PRED && vi < 0) val = 0u;
    return val;
}

#define SLOT(p) ((p) < 16 ? W[(p)] : X[(p) - 16])

// Paired-tap block: 8 step-pairs; T holds taps for steps (2jj, 2jj+1).
template <bool PRED, bool LOADU>
__device__ __forceinline__ void conv_block(const u32* __restrict__ ub2,
                                           const uint4* klds4,
                                           float (&acc)[LT], u32 (&W)[16], u32 (&X)[16],
                                           int ubase, int soff) {
    int j0 = soff >> 1;
    uint4 T = klds4[j0 * 64];
    #pragma unroll
    for (int jj = 0; jj < 8; ++jj) {
        uint4 Tn = T;
        if (jj < 7) Tn = klds4[(j0 + jj + 1) * 64];
        int k0i = 2 * jj;
        u32 nv0 = 0u, nv1 = 0u;
        if (LOADU) {
            nv0 = load_v<PRED>(ub2, ubase + k0i);
            nv1 = load_v<PRED>(ub2, ubase + k0i + 1);
        }
        // even step k = 2jj: kx = T.x, ky = T.y
        {
            half2_t kx = __builtin_bit_cast(half2_t, T.x);
            half2_t ky = __builtin_bit_cast(half2_t, T.y);
            #pragma unroll
            for (int m = 0; m < 8; ++m) {
                half2_t ve = __builtin_bit_cast(half2_t, SLOT(k0i + m));
                half2_t vo = __builtin_bit_cast(half2_t, SLOT(k0i + m + 1));
                acc[2 * m]     = fdot2(ve, ky, acc[2 * m]);
                acc[2 * m + 1] = fdot2(vo, kx, acc[2 * m + 1]);
            }
            if (LOADU) W[k0i] = nv0;
        }
        // odd step k = 2jj+1: kx = T.z, ky = T.w
        {
            int k = k0i + 1;
            half2_t kx = __builtin_bit_cast(half2_t, T.z);
            half2_t ky = __builtin_bit_cast(half2_t, T.w);
            #pragma unroll
            for (int m = 0; m < 8; ++m) {
                half2_t ve = __builtin_bit_cast(half2_t, SLOT(k + m));
                half2_t vo = __builtin_bit_cast(half2_t, SLOT(k + m + 1));
                acc[2 * m]     = fdot2(ve, ky, acc[2 * m]);
                acc[2 * m + 1] = fdot2(vo, kx, acc[2 * m + 1]);
            }
            if (LOADU) W[k] = nv1;
        }
        T = Tn;
    }
}

template <bool PRED>
__device__ __forceinline__ void conv_all(const u32* __restrict__ ub2,
                                         const uint4* klds4,
                                         float (&acc)[LT], u32 (&A)[16], u32 (&B)[16],
                                         int Vm1) {
    #pragma unroll
    for (int j = 0; j < 16; ++j) A[j] = load_v<PRED>(ub2, Vm1 + j);
    #pragma unroll
    for (int j = 0; j < 16; ++j) B[j] = load_v<PRED>(ub2, Vm1 + 16 + j);
    conv_block<PRED, true >(ub2, klds4, acc, A, B, Vm1 + 32, 0);    // sb0
    conv_block<PRED, true >(ub2, klds4, acc, B, A, Vm1 + 48, 16);   // sb1
    conv_block<PRED, true >(ub2, klds4, acc, A, B, Vm1 + 64, 32);   // sb2
    conv_block<PRED, true >(ub2, klds4, acc, B, A, Vm1 + 80, 48);   // sb3
    // sb4: loads v[Vm1+96..111] = v[l0/2..l0/2+15] into A (epilogue data)
    conv_block<PRED, true >(ub2, klds4, acc, A, B, Vm1 + 96, 64);
    // sb5: no loads; A preserved
    conv_block<PRED, false>(ub2, klds4, acc, B, A, 0, 80);
}

__global__ __launch_bounds__(512, 2) void conv_kernel(const u32* __restrict__ u2,
                                                      const float* __restrict__ KT,
                                                      const float* __restrict__ Dp,
                                                      float* __restrict__ y) {
    __shared__ uint4 KLS[48 * 64];       // 48 KB: paired taps for 64 h's
    int tid = threadIdx.x;
    int lane = tid & 63;
    int g = tid >> 6;                    // wave = l-subtile (0..7)
    int blk = blockIdx.x;                // 2048 blocks: 8 hg x 32 tg x 8 b
    int hg = blk & 7;
    int tg = (blk >> 3) & 31;
    int b = blk >> 8;
    int h = hg * 64 + lane;
    int l0 = (tg * 8 + g) * LT;
    const float* ktg = KT + hg * 64;
    // stage as uint4 KL4[j*64+hh] = (kx(2j),ky(2j),kx(2j+1),ky(2j+1)),
    // built inline from KT (pack_k fused; bit-identical rounding):
    //   kx(s) = (lo K[191-2s], hi K[190-2s]); ky(s) = (lo K[192-2s]|0, hi K[191-2s])
    #pragma unroll
    for (int it = 0; it < 6; ++it) {
        int i = it * 512 + tid;          // entry index, 3072 total
        int j = i >> 6;
        int hh = i & 63;
        int tb = 188 - 4 * j;            // K indices tb..tb+4 used
        float k188 = ktg[(size_t)(tb + 0) * HH + hh];
        float k189 = ktg[(size_t)(tb + 1) * HH + hh];
        float k190 = ktg[(size_t)(tb + 2) * HH + hh];
        float k191 = ktg[(size_t)(tb + 3) * HH + hh];
        float k192 = (j > 0) ? ktg[(size_t)(tb + 4) * HH + hh] : 0.0f;
        half2_t x0, y0, x1, y1;
        x0.x = (_Float16)k191; x0.y = (_Float16)k190;   // kx(2j)
        y0.x = (_Float16)k192; y0.y = (_Float16)k191;   // ky(2j)
        x1.x = (_Float16)k189; x1.y = (_Float16)k188;   // kx(2j+1)
        y1.x = (_Float16)k190; y1.y = (_Float16)k189;   // ky(2j+1)
        KLS[j * 64 + hh] = make_uint4(__builtin_bit_cast(u32, x0), __builtin_bit_cast(u32, y0),
                                      __builtin_bit_cast(u32, x1), __builtin_bit_cast(u32, y1));
    }
    __syncthreads();
    const u32* ub2 = u2 + (size_t)b * (LL / 2) * HH + h;
    const uint4* klds4 = &KLS[lane];
    int Vm1 = l0 / 2 - NS;
    float acc[LT];
    u32 A[16], B[16];
    #pragma unroll
    for (int j = 0; j < LT; ++j) acc[j] = 0.0f;
    if (l0 >= TT) {
        conv_all<false>(ub2, klds4, acc, A, B, Vm1);
    } else {
        conv_all<true>(ub2, klds4, acc, A, B, Vm1);
    }
    float dv = Dp[h];
    float k0f = KT[h];          // K[0]
    float ce = k0f + dv;
    float* yb = y + ((size_t)b * LL + l0) * HH + h;
    // A[m] = v[l0/2+m] = (u[l0+2m], u[l0+2m+1])
    #pragma unroll
    for (int m = 0; m < 8; ++m) {
        half2_t av = __builtin_bit_cast(half2_t, A[m]);
        float ue = (float)av.x;
        float uo = (float)av.y;
        yb[(size_t)(2 * m) * HH]     = acc[2 * m] + ce * ue;
        yb[(size_t)(2 * m + 1) * HH] = acc[2 * m + 1] + dv * uo;
    }
}

// ---------------------------------------------------------------------------
extern "C" void kernel_launch(void* const* d_in, const int* in_sizes, int n_in,
                              void* d_out, int out_size, void* d_ws, size_t ws_size,
                              hipStream_t stream) {
    const float* x   = (const float*)d_in[0];
    const float* lnw = (const float*)d_in[1];
    const float* lnb = (const float*)d_in[2];
    const float* LR  = (const float*)d_in[3];
    const float* LI  = (const float*)d_in[4];
    const float* Cr  = (const float*)d_in[5];
    const float* Ci  = (const float*)d_in[6];
    const float* Dp  = (const float*)d_in[7];
    float* y  = (float*)d_out;

    float2* Cpk = (float2*)d_ws;                      // NN*HH float2   (2 MB)
    float2* PQ  = Cpk + (size_t)NN * HH;              // NN*TT float2   (0.75 MB)
    float*  KT  = (float*)(PQ + (size_t)NN * TT);     // TT*HH          (384 KB)
    uint2*  KQ  = (uint2*)(KT + (size_t)TT * HH);     // (unused; layout keep)
    u32*    u2  = (u32*)(KQ + (size_t)NS * HH);       // BB*(LL/2)*HH + 16-row pad

    prep_kernel<<<LN_BLKS + 64 + NN, 256, 0, stream>>>(x, lnw, lnb, Cr, Ci,
                                                       LR, LI, u2, Cpk, PQ);
    build_kt<<<(TT / 2) * 4, 512, 0, stream>>>(Cpk, PQ, KT);
    conv_kernel<<<BB * (LL / (8 * LT)) * 8, 512, 0, stream>>>(u2, KT, Dp, y);
}